// Round 6
// baseline (745.624 us; speedup 1.0000x reference)
//
#include <hip/hip_runtime.h>
#include <hip/hip_bf16.h>

#define EMB 128

typedef __attribute__((ext_vector_type(8))) short short8;   // 8 bf16 (4 VGPRs)
typedef __attribute__((ext_vector_type(4))) float floatx4;  // MFMA C/D

// 26 valid (ok, di, ol) message combos: deltas = {1,2,-1,-2}, ol = ok+delta in [0,8)
static constexpr int OKv[26] = {0,0,1,1,1,2,2,2,2,3,3,3,3,4,4,4,4,5,5,5,5,6,6,6,7,7};
static constexpr int DIv[26] = {0,1,0,1,2,0,1,2,3,0,1,2,3,0,1,2,3,0,1,2,3,0,2,3,2,3};
static constexpr int OLv[26] = {1,2,2,3,0,3,4,1,0,4,5,2,1,5,6,3,2,6,7,4,3,7,5,4,6,5};

__device__ __forceinline__ float4 ld4(const float* p) { return *(const float4*)p; }

// round-to-nearest-even bf16 bits of x, kept in the TOP 16 bits (low 16 zero)
__device__ __forceinline__ unsigned bf16_rne_hi(float x) {
  unsigned u = __float_as_uint(x);
  return (u + 0x7FFFu + ((u >> 16) & 1u)) & 0xFFFF0000u;
}
__device__ __forceinline__ float bf16hi_f(float x) {
  return __uint_as_float(bf16_rne_hi(x));
}
// HW packed cvt: a -> low 16, b -> high 16 (v_cvt_pk_bf16_f32 on gfx950)
__device__ __forceinline__ unsigned cvt_pk_bf16(float a, float b) {
  __hip_bfloat162 h = __float22bfloat162_rn(make_float2(a, b));
  unsigned r; __builtin_memcpy(&r, &h, 4); return r;
}

union FragU { unsigned u[4]; uint4 q; short8 v; };

// out[g] = b_pred[0], g < 64
__global__ void out_init_kernel(float* __restrict__ out, const float* __restrict__ b_pred) {
  out[threadIdx.x] = b_pred[0];
}

// lin32[v][e] = emb_x[v] @ w_ti + b_ti  — lin[node] = lin32[x[node]] (only 32 distinct)
__global__ void lin_kernel(const float* __restrict__ emb_x,
                           const float* __restrict__ w_ti, const float* __restrict__ b_ti,
                           float* __restrict__ lin32) {
  const int n = blockIdx.x;      // x-value 0..31
  const int e = threadIdx.x;
  const float* xr = emb_x + n * EMB;
  float a0 = b_ti[e], a1 = 0.f, a2 = 0.f, a3 = 0.f;
  #pragma unroll 4
  for (int f = 0; f < EMB; f += 4) {
    a0 = fmaf(xr[f + 0], w_ti[(f + 0) * EMB + e], a0);
    a1 = fmaf(xr[f + 1], w_ti[(f + 1) * EMB + e], a1);
    a2 = fmaf(xr[f + 2], w_ti[(f + 2) * EMB + e], a2);
    a3 = fmaf(xr[f + 3], w_ti[(f + 3) * EMB + e], a3);
  }
  lin32[n * EMB + e] = (a0 + a1) + (a2 + a3);
}

// Pre-pack w_conv into MFMA B-fragment order, split into bf16 hi/lo planes.
// frag(l,t,u,pass): B[k][n]: n = lane&15, k = (lane>>4)*8 + j. uint4/lane.
__global__ void wfrag_kernel(const float* __restrict__ w_conv, uint4* __restrict__ wfrag) {
  const int id   = blockIdx.x * 256 + threadIdx.x;   // 320 frags * 64 lanes
  const int lane = id & 63;
  const int f    = id >> 6;
  const int pass = f & 1;           // 0 = hi, 1 = lo
  const int u    = (f >> 1) & 7;    // N-tile
  const int t    = (f >> 4) & 3;    // K-tile
  const int l    = f >> 6;          // layer
  const int q    = lane >> 4, n = lane & 15;
  unsigned w[4] = {0u, 0u, 0u, 0u};
  #pragma unroll
  for (int j = 0; j < 8; ++j) {
    const int ff = t * 32 + q * 8 + j;
    const int c  = u * 16 + n;
    float val = w_conv[l * (EMB * EMB) + ff * EMB + c];
    if (pass) val = val - bf16hi_f(val);
    const unsigned b = bf16_rne_hi(val);
    w[j >> 1] |= (j & 1) ? b : (b >> 16);
  }
  wfrag[id] = make_uint4(w[0], w[1], w[2], w[3]);
}

// Block = root node i (8 pairs = 64 M-rows, row = wv*16 + 2k + h).
// Per layer: flat VALU message pass (ea read from GLOBAL — L1-resident 8 KB,
//   keeps the 26 b128/wave-layer off the saturated LDS pipe); HW-cvt bf16
//   hi/lo pack written in A-fragment order to fragbuf (32 KB = whole LDS
//   block -> 5 blocks/CU); wave w MFMAs N-tiles {2w,2w+1} for all 4 M-tiles;
//   epilogue via fp32 overlay of fragbuf (XOR-16 col swizzle).
__global__ __launch_bounds__(256)
__attribute__((amdgpu_waves_per_eu(5, 5)))
void i2gnn_mfma(
    const int* __restrict__ x,
    const int* __restrict__ edge_attr,
    const int* __restrict__ tuplefeat,
    const float* __restrict__ emb_x,
    const float* __restrict__ emb_tf,
    const float* __restrict__ emb_ea,
    const float* __restrict__ lin32,
    const float* __restrict__ b_conv,
    const float* __restrict__ w_pred,
    const uint4* __restrict__ wfrag,
    float* __restrict__ out)
{
  __shared__ uint4 fragbuf[2048];      // 32 KB exactly: [plane][mtile][t][row16][q]
  float* epi = (float*)fragbuf;        // overlay: fp32 [64][128] after barrier

  const int tid = threadIdx.x;
  const int wv = tid >> 6, lane = tid & 63;
  const int h = lane >> 5, l5 = lane & 31;
  const int c0 = l5 << 2;              // 4 owned channels (flat layout)
  const int m16 = lane & 15, q2 = lane >> 4;
  const int tq = l5 >> 3, qq = (l5 >> 1) & 3, pp = l5 & 1;  // A-write coords

  const int i = blockIdx.x;
  const int jj = wv * 2 + h;           // this half-wave's pair slot
  const int ibase = i & ~63, io = i & 63;
  const int jnode = ibase + ((io + jj) & 63);
  const int g = i >> 6;
  const int p = i * 8 + jj;

  // 26 edge attrs (4 bits each) — function of i only
  unsigned pk[4] = {0u, 0u, 0u, 0u};
  #pragma unroll
  for (int m = 0; m < 26; ++m) {
    const int kg = ibase + ((io + OKv[m]) & 63);
    const unsigned a = (unsigned)edge_attr[(kg << 2) + DIv[m]];
    pk[m >> 3] |= a << ((m & 7) * 4);
  }

  // tupleinit: X[k] = xe[i] * lin32[x[jnode]] * tf[tuple]
  const float4 xe = ld4(emb_x + x[i] * EMB + c0);
  const float4 lj = ld4(lin32 + x[jnode] * EMB + c0);
  float4 X[8];
  #pragma unroll
  for (int k = 0; k < 8; ++k) {
    const int t = (p << 3) + k;
    const int2 tf2 = *(const int2*)(tuplefeat + (t << 1));
    const int row = (l5 < 16) ? tf2.x : tf2.y;
    const float4 tf = ld4(emb_tf + (row << 6) + (c0 & 63));
    X[k] = make_float4(xe.x * lj.x * tf.x, xe.y * lj.y * tf.y,
                       xe.z * lj.z * tf.z, xe.w * lj.w * tf.w);
  }

  const int u0 = wv * 2;
  uint2* f2 = (uint2*)fragbuf;

  for (int l = 0; l < 5; ++l) {
    // ---- message pass (fp32 VALU; ea straight from global/L1) ----
    float4 acc[8];
    #pragma unroll
    for (int k = 0; k < 8; ++k) acc[k] = make_float4(0.f, 0.f, 0.f, 0.f);
    #pragma unroll
    for (int m = 0; m < 26; ++m) {
      const unsigned attr = (pk[m >> 3] >> ((m & 7) * 4)) & 15u;
      const float4 ea = ld4(emb_ea + attr * EMB + c0);
      acc[OKv[m]].x = fmaf(X[OLv[m]].x, ea.x, acc[OKv[m]].x);
      acc[OKv[m]].y = fmaf(X[OLv[m]].y, ea.y, acc[OKv[m]].y);
      acc[OKv[m]].z = fmaf(X[OLv[m]].z, ea.z, acc[OKv[m]].z);
      acc[OKv[m]].w = fmaf(X[OLv[m]].w, ea.w, acc[OKv[m]].w);
    }
    // ---- HW-cvt pack hi/lo bf16, write in A-fragment order (row = 2k+h) ----
    #pragma unroll
    for (int k = 0; k < 8; ++k) {
      const float4 a = acc[k];
      const unsigned h01 = cvt_pk_bf16(a.x, a.y);
      const unsigned h23 = cvt_pk_bf16(a.z, a.w);
      const float rx = a.x - __uint_as_float(h01 << 16);
      const float ry = a.y - __uint_as_float(h01 & 0xFFFF0000u);
      const float rz = a.z - __uint_as_float(h23 << 16);
      const float rw = a.w - __uint_as_float(h23 & 0xFFFF0000u);
      const int row = 2 * k + h;
      const int gb = (wv * 4 + tq) * 64 + row * 4 + qq;   // plane-0 granule
      f2[gb * 2 + pp] = make_uint2(h01, h23);
      f2[(1024 + gb) * 2 + pp] = make_uint2(cvt_pk_bf16(rx, ry), cvt_pk_bf16(rz, rw));
    }
    __syncthreads();   // A-planes complete

    // ---- MFMA: wave computes u0,u0+1 for all 4 M-tiles ----
    floatx4 C[2][4];
    #pragma unroll
    for (int v = 0; v < 2; ++v)
      #pragma unroll
      for (int mt = 0; mt < 4; ++mt) C[v][mt] = (floatx4){0.f, 0.f, 0.f, 0.f};

    #pragma unroll
    for (int t = 0; t < 4; ++t) {
      const uint4* wp0 = wfrag + ((((l * 4 + t) * 8 + u0) * 2) << 6);
      FragU B0h, B0l, B1h, B1l;
      B0h.q = wp0[lane];        B0l.q = wp0[64 + lane];
      B1h.q = wp0[128 + lane];  B1l.q = wp0[192 + lane];
      #pragma unroll
      for (int mt = 0; mt < 4; ++mt) {
        const int gA = (mt * 4 + t) * 64 + m16 * 4 + q2;
        FragU Ah, Al;
        Ah.q = fragbuf[gA];
        Al.q = fragbuf[1024 + gA];
        C[0][mt] = __builtin_amdgcn_mfma_f32_16x16x32_bf16(Ah.v, B0h.v, C[0][mt], 0, 0, 0);
        C[0][mt] = __builtin_amdgcn_mfma_f32_16x16x32_bf16(Al.v, B0h.v, C[0][mt], 0, 0, 0);
        C[0][mt] = __builtin_amdgcn_mfma_f32_16x16x32_bf16(Ah.v, B0l.v, C[0][mt], 0, 0, 0);
        C[1][mt] = __builtin_amdgcn_mfma_f32_16x16x32_bf16(Ah.v, B1h.v, C[1][mt], 0, 0, 0);
        C[1][mt] = __builtin_amdgcn_mfma_f32_16x16x32_bf16(Al.v, B1h.v, C[1][mt], 0, 0, 0);
        C[1][mt] = __builtin_amdgcn_mfma_f32_16x16x32_bf16(Ah.v, B1l.v, C[1][mt], 0, 0, 0);
      }
    }
    __syncthreads();   // all A-frag reads done; fragbuf reusable as epi

    // ---- epilogue: C (row=q2*4+r, ch=u*16+m16) -> epi -> flat update ----
    #pragma unroll
    for (int v = 0; v < 2; ++v)
      #pragma unroll
      for (int mt = 0; mt < 4; ++mt)
        #pragma unroll
        for (int r = 0; r < 4; ++r) {
          const int row = mt * 16 + q2 * 4 + r;
          const int cs  = ((u0 + v) * 16 + m16) ^ ((q2 & 1) << 4); // (row>>2)&1 == q2&1
          epi[row * 128 + cs] = C[v][mt][r];
        }
    __syncthreads();
    const float4 b4 = ld4(b_conv + l * EMB + c0);
    #pragma unroll
    for (int k = 0; k < 8; ++k) {
      const int row = wv * 16 + 2 * k + h;
      const int cs  = c0 ^ ((((2 * k + h) >> 2) & 1) << 4);
      const float4 o = *(const float4*)(epi + row * 128 + cs);
      X[k].x += fmaxf(o.x + b4.x, 0.f);
      X[k].y += fmaxf(o.y + b4.y, 0.f);
      X[k].z += fmaxf(o.z + b4.z, 0.f);
      X[k].w += fmaxf(o.w + b4.w, 0.f);
    }
    __syncthreads();   // epi reads done before next layer's A-writes
  }

  // ---- pooling: max over k, dot w_pred, per-graph atomic sum ----
  float4 pv = X[0];
  #pragma unroll
  for (int k = 1; k < 8; ++k) {
    pv.x = fmaxf(pv.x, X[k].x);
    pv.y = fmaxf(pv.y, X[k].y);
    pv.z = fmaxf(pv.z, X[k].z);
    pv.w = fmaxf(pv.w, X[k].w);
  }
  const float4 wp = ld4(w_pred + c0);
  float s = pv.x * wp.x + pv.y * wp.y + pv.z * wp.z + pv.w * wp.w;
  #pragma unroll
  for (int off = 16; off; off >>= 1) s += __shfl_xor(s, off, 64);
  if (l5 == 0) atomicAdd(out + g, s);
}

extern "C" void kernel_launch(void* const* d_in, const int* in_sizes, int n_in,
                              void* d_out, int out_size, void* d_ws, size_t ws_size,
                              hipStream_t stream) {
  const int*   x         = (const int*)d_in[0];
  const int*   edge_attr = (const int*)d_in[1];
  const int*   tuplefeat = (const int*)d_in[2];
  const float* emb_x     = (const float*)d_in[12];
  const float* emb_ea    = (const float*)d_in[13];
  const float* emb_tf    = (const float*)d_in[14];
  const float* w_ti      = (const float*)d_in[15];
  const float* b_ti      = (const float*)d_in[16];
  const float* w_conv    = (const float*)d_in[17];
  const float* b_conv    = (const float*)d_in[18];
  const float* w_pred    = (const float*)d_in[19];
  const float* b_pred    = (const float*)d_in[20];
  float* out = (float*)d_out;
  float* lin32 = (float*)d_ws;                               // 32*128 fp32 = 16 KB
  uint4* wfrag = (uint4*)((char*)d_ws + 32 * EMB * 4);       // 320 KB B-fragments

  hipLaunchKernelGGL(out_init_kernel, dim3(1), dim3(64), 0, stream, out, b_pred);
  hipLaunchKernelGGL(lin_kernel, dim3(32), dim3(EMB), 0, stream, emb_x, w_ti, b_ti, lin32);
  hipLaunchKernelGGL(wfrag_kernel, dim3(80), dim3(256), 0, stream, w_conv, wfrag);
  hipLaunchKernelGGL(i2gnn_mfma, dim3(4096), dim3(256), 0, stream,
                     x, edge_attr, tuplefeat, emb_x, emb_tf, emb_ea, lin32,
                     b_conv, w_pred, wfrag, out);
}

// Round 7
// 316.753 us; speedup vs baseline: 2.3540x; 2.3540x over previous
//
#include <hip/hip_runtime.h>
#include <hip/hip_bf16.h>

#define EMB 128

typedef __attribute__((ext_vector_type(8))) short short8;   // 8 bf16 (4 VGPRs)
typedef __attribute__((ext_vector_type(4))) float floatx4;  // MFMA C/D

// 26 valid (ok, di, ol) message combos: deltas = {1,2,-1,-2}, ol = ok+delta in [0,8)
static constexpr int OKv[26] = {0,0,1,1,1,2,2,2,2,3,3,3,3,4,4,4,4,5,5,5,5,6,6,6,7,7};
static constexpr int DIv[26] = {0,1,0,1,2,0,1,2,3,0,1,2,3,0,1,2,3,0,1,2,3,0,2,3,2,3};
static constexpr int OLv[26] = {1,2,2,3,0,3,4,1,0,4,5,2,1,5,6,3,2,6,7,4,3,7,5,4,6,5};

__device__ __forceinline__ float4 ld4(const float* p) { return *(const float4*)p; }

// round-to-nearest-even bf16 bits of x, kept in the TOP 16 bits (low 16 zero)
__device__ __forceinline__ unsigned bf16_rne_hi(float x) {
  unsigned u = __float_as_uint(x);
  return (u + 0x7FFFu + ((u >> 16) & 1u)) & 0xFFFF0000u;
}
__device__ __forceinline__ float bf16hi_f(float x) {
  return __uint_as_float(bf16_rne_hi(x));
}
// HW packed cvt: a -> low 16, b -> high 16 (v_cvt_pk_bf16_f32 on gfx950)
__device__ __forceinline__ unsigned cvt_pk_bf16(float a, float b) {
  __hip_bfloat162 h = __float22bfloat162_rn(make_float2(a, b));
  unsigned r; __builtin_memcpy(&r, &h, 4); return r;
}

union FragU { unsigned u[4]; uint4 q; short8 v; };

// out[g] = b_pred[0], g < 64
__global__ void out_init_kernel(float* __restrict__ out, const float* __restrict__ b_pred) {
  out[threadIdx.x] = b_pred[0];
}

// lin32[v][e] = emb_x[v] @ w_ti + b_ti  — lin[node] = lin32[x[node]] (only 32 distinct)
__global__ void lin_kernel(const float* __restrict__ emb_x,
                           const float* __restrict__ w_ti, const float* __restrict__ b_ti,
                           float* __restrict__ lin32) {
  const int n = blockIdx.x;      // x-value 0..31
  const int e = threadIdx.x;
  const float* xr = emb_x + n * EMB;
  float a0 = b_ti[e], a1 = 0.f, a2 = 0.f, a3 = 0.f;
  #pragma unroll 4
  for (int f = 0; f < EMB; f += 4) {
    a0 = fmaf(xr[f + 0], w_ti[(f + 0) * EMB + e], a0);
    a1 = fmaf(xr[f + 1], w_ti[(f + 1) * EMB + e], a1);
    a2 = fmaf(xr[f + 2], w_ti[(f + 2) * EMB + e], a2);
    a3 = fmaf(xr[f + 3], w_ti[(f + 3) * EMB + e], a3);
  }
  lin32[n * EMB + e] = (a0 + a1) + (a2 + a3);
}

// Pre-pack w_conv into MFMA B-fragment order, split into bf16 hi/lo planes.
// frag(l,t,u,pass): B[k][n]: n = lane&15, k = (lane>>4)*8 + j. uint4/lane.
__global__ void wfrag_kernel(const float* __restrict__ w_conv, uint4* __restrict__ wfrag) {
  const int id   = blockIdx.x * 256 + threadIdx.x;   // 320 frags * 64 lanes
  const int lane = id & 63;
  const int f    = id >> 6;
  const int pass = f & 1;           // 0 = hi, 1 = lo
  const int u    = (f >> 1) & 7;    // N-tile
  const int t    = (f >> 4) & 3;    // K-tile
  const int l    = f >> 6;          // layer
  const int q    = lane >> 4, n = lane & 15;
  unsigned w[4] = {0u, 0u, 0u, 0u};
  #pragma unroll
  for (int j = 0; j < 8; ++j) {
    const int ff = t * 32 + q * 8 + j;
    const int c  = u * 16 + n;
    float val = w_conv[l * (EMB * EMB) + ff * EMB + c];
    if (pass) val = val - bf16hi_f(val);
    const unsigned b = bf16_rne_hi(val);
    w[j >> 1] |= (j & 1) ? b : (b >> 16);
  }
  wfrag[id] = make_uint4(w[0], w[1], w[2], w[3]);
}

// Block = root node i (8 pairs = 64 M-rows, row = wv*16 + 2k + h).
// Per layer: flat VALU message pass (ea read from GLOBAL — L1-resident 8 KB,
//   keeps those 26 b128/wave-layer off the LDS pipe); HW-cvt bf16 hi/lo pack
//   written in A-fragment order to fragbuf (32 KB); wave w MFMAs N-tiles
//   {2w,2w+1} for all 4 M-tiles; epilogue via fp32 overlay (XOR-16 swizzle).
// NO occupancy attribute: twice measured (R1 launch_bounds(256,4), R6
// waves_per_eu(5,5)) that forcing a budget makes the allocator pick a tiny
// VGPR count and spill ~0.5-1.6 GB to scratch. Unconstrained = ~108 VGPR,
// zero spill, 4 blocks/CU.
__global__ __launch_bounds__(256)
void i2gnn_mfma(
    const int* __restrict__ x,
    const int* __restrict__ edge_attr,
    const int* __restrict__ tuplefeat,
    const float* __restrict__ emb_x,
    const float* __restrict__ emb_tf,
    const float* __restrict__ emb_ea,
    const float* __restrict__ lin32,
    const float* __restrict__ b_conv,
    const float* __restrict__ w_pred,
    const uint4* __restrict__ wfrag,
    float* __restrict__ out)
{
  __shared__ uint4 fragbuf[2048];      // 32 KB exactly: [plane][mtile][t][row16][q]
  float* epi = (float*)fragbuf;        // overlay: fp32 [64][128] after barrier

  const int tid = threadIdx.x;
  const int wv = tid >> 6, lane = tid & 63;
  const int h = lane >> 5, l5 = lane & 31;
  const int c0 = l5 << 2;              // 4 owned channels (flat layout)
  const int m16 = lane & 15, q2 = lane >> 4;
  const int tq = l5 >> 3, qq = (l5 >> 1) & 3, pp = l5 & 1;  // A-write coords

  const int i = blockIdx.x;
  const int jj = wv * 2 + h;           // this half-wave's pair slot
  const int ibase = i & ~63, io = i & 63;
  const int jnode = ibase + ((io + jj) & 63);
  const int g = i >> 6;
  const int p = i * 8 + jj;

  // 26 edge attrs (4 bits each) — function of i only
  unsigned pk[4] = {0u, 0u, 0u, 0u};
  #pragma unroll
  for (int m = 0; m < 26; ++m) {
    const int kg = ibase + ((io + OKv[m]) & 63);
    const unsigned a = (unsigned)edge_attr[(kg << 2) + DIv[m]];
    pk[m >> 3] |= a << ((m & 7) * 4);
  }

  // tupleinit: X[k] = xe[i] * lin32[x[jnode]] * tf[tuple]
  const float4 xe = ld4(emb_x + x[i] * EMB + c0);
  const float4 lj = ld4(lin32 + x[jnode] * EMB + c0);
  float4 X[8];
  #pragma unroll
  for (int k = 0; k < 8; ++k) {
    const int t = (p << 3) + k;
    const int2 tf2 = *(const int2*)(tuplefeat + (t << 1));
    const int row = (l5 < 16) ? tf2.x : tf2.y;
    const float4 tf = ld4(emb_tf + (row << 6) + (c0 & 63));
    X[k] = make_float4(xe.x * lj.x * tf.x, xe.y * lj.y * tf.y,
                       xe.z * lj.z * tf.z, xe.w * lj.w * tf.w);
  }

  const int u0 = wv * 2;
  uint2* f2 = (uint2*)fragbuf;

  for (int l = 0; l < 5; ++l) {
    // ---- message pass (fp32 VALU; ea straight from global/L1) ----
    float4 acc[8];
    #pragma unroll
    for (int k = 0; k < 8; ++k) acc[k] = make_float4(0.f, 0.f, 0.f, 0.f);
    #pragma unroll
    for (int m = 0; m < 26; ++m) {
      const unsigned attr = (pk[m >> 3] >> ((m & 7) * 4)) & 15u;
      const float4 ea = ld4(emb_ea + attr * EMB + c0);
      acc[OKv[m]].x = fmaf(X[OLv[m]].x, ea.x, acc[OKv[m]].x);
      acc[OKv[m]].y = fmaf(X[OLv[m]].y, ea.y, acc[OKv[m]].y);
      acc[OKv[m]].z = fmaf(X[OLv[m]].z, ea.z, acc[OKv[m]].z);
      acc[OKv[m]].w = fmaf(X[OLv[m]].w, ea.w, acc[OKv[m]].w);
    }
    // ---- HW-cvt pack hi/lo bf16, write in A-fragment order (row = 2k+h) ----
    #pragma unroll
    for (int k = 0; k < 8; ++k) {
      const float4 a = acc[k];
      const unsigned h01 = cvt_pk_bf16(a.x, a.y);
      const unsigned h23 = cvt_pk_bf16(a.z, a.w);
      const float rx = a.x - __uint_as_float(h01 << 16);
      const float ry = a.y - __uint_as_float(h01 & 0xFFFF0000u);
      const float rz = a.z - __uint_as_float(h23 << 16);
      const float rw = a.w - __uint_as_float(h23 & 0xFFFF0000u);
      const int row = 2 * k + h;
      const int gb = (wv * 4 + tq) * 64 + row * 4 + qq;   // plane-0 granule
      f2[gb * 2 + pp] = make_uint2(h01, h23);
      f2[(1024 + gb) * 2 + pp] = make_uint2(cvt_pk_bf16(rx, ry), cvt_pk_bf16(rz, rw));
    }
    __syncthreads();   // A-planes complete

    // ---- MFMA: wave computes u0,u0+1 for all 4 M-tiles ----
    floatx4 C[2][4];
    #pragma unroll
    for (int v = 0; v < 2; ++v)
      #pragma unroll
      for (int mt = 0; mt < 4; ++mt) C[v][mt] = (floatx4){0.f, 0.f, 0.f, 0.f};

    #pragma unroll
    for (int t = 0; t < 4; ++t) {
      const uint4* wp0 = wfrag + ((((l * 4 + t) * 8 + u0) * 2) << 6);
      FragU B0h, B0l, B1h, B1l;
      B0h.q = wp0[lane];        B0l.q = wp0[64 + lane];
      B1h.q = wp0[128 + lane];  B1l.q = wp0[192 + lane];
      #pragma unroll
      for (int mt = 0; mt < 4; ++mt) {
        const int gA = (mt * 4 + t) * 64 + m16 * 4 + q2;
        FragU Ah, Al;
        Ah.q = fragbuf[gA];
        Al.q = fragbuf[1024 + gA];
        C[0][mt] = __builtin_amdgcn_mfma_f32_16x16x32_bf16(Ah.v, B0h.v, C[0][mt], 0, 0, 0);
        C[0][mt] = __builtin_amdgcn_mfma_f32_16x16x32_bf16(Al.v, B0h.v, C[0][mt], 0, 0, 0);
        C[0][mt] = __builtin_amdgcn_mfma_f32_16x16x32_bf16(Ah.v, B0l.v, C[0][mt], 0, 0, 0);
        C[1][mt] = __builtin_amdgcn_mfma_f32_16x16x32_bf16(Ah.v, B1h.v, C[1][mt], 0, 0, 0);
        C[1][mt] = __builtin_amdgcn_mfma_f32_16x16x32_bf16(Al.v, B1h.v, C[1][mt], 0, 0, 0);
        C[1][mt] = __builtin_amdgcn_mfma_f32_16x16x32_bf16(Ah.v, B1l.v, C[1][mt], 0, 0, 0);
      }
    }
    __syncthreads();   // all A-frag reads done; fragbuf reusable as epi

    // ---- epilogue: C (row=q2*4+r, ch=u*16+m16) -> epi -> flat update ----
    #pragma unroll
    for (int v = 0; v < 2; ++v)
      #pragma unroll
      for (int mt = 0; mt < 4; ++mt)
        #pragma unroll
        for (int r = 0; r < 4; ++r) {
          const int row = mt * 16 + q2 * 4 + r;
          const int cs  = ((u0 + v) * 16 + m16) ^ ((q2 & 1) << 4); // (row>>2)&1 == q2&1
          epi[row * 128 + cs] = C[v][mt][r];
        }
    __syncthreads();
    const float4 b4 = ld4(b_conv + l * EMB + c0);
    #pragma unroll
    for (int k = 0; k < 8; ++k) {
      const int row = wv * 16 + 2 * k + h;
      const int cs  = c0 ^ ((((2 * k + h) >> 2) & 1) << 4);
      const float4 o = *(const float4*)(epi + row * 128 + cs);
      X[k].x += fmaxf(o.x + b4.x, 0.f);
      X[k].y += fmaxf(o.y + b4.y, 0.f);
      X[k].z += fmaxf(o.z + b4.z, 0.f);
      X[k].w += fmaxf(o.w + b4.w, 0.f);
    }
    __syncthreads();   // epi reads done before next layer's A-writes
  }

  // ---- pooling: max over k, dot w_pred, per-graph atomic sum ----
  float4 pv = X[0];
  #pragma unroll
  for (int k = 1; k < 8; ++k) {
    pv.x = fmaxf(pv.x, X[k].x);
    pv.y = fmaxf(pv.y, X[k].y);
    pv.z = fmaxf(pv.z, X[k].z);
    pv.w = fmaxf(pv.w, X[k].w);
  }
  const float4 wp = ld4(w_pred + c0);
  float s = pv.x * wp.x + pv.y * wp.y + pv.z * wp.z + pv.w * wp.w;
  #pragma unroll
  for (int off = 16; off; off >>= 1) s += __shfl_xor(s, off, 64);
  if (l5 == 0) atomicAdd(out + g, s);
}

extern "C" void kernel_launch(void* const* d_in, const int* in_sizes, int n_in,
                              void* d_out, int out_size, void* d_ws, size_t ws_size,
                              hipStream_t stream) {
  const int*   x         = (const int*)d_in[0];
  const int*   edge_attr = (const int*)d_in[1];
  const int*   tuplefeat = (const int*)d_in[2];
  const float* emb_x     = (const float*)d_in[12];
  const float* emb_ea    = (const float*)d_in[13];
  const float* emb_tf    = (const float*)d_in[14];
  const float* w_ti      = (const float*)d_in[15];
  const float* b_ti      = (const float*)d_in[16];
  const float* w_conv    = (const float*)d_in[17];
  const float* b_conv    = (const float*)d_in[18];
  const float* w_pred    = (const float*)d_in[19];
  const float* b_pred    = (const float*)d_in[20];
  float* out = (float*)d_out;
  float* lin32 = (float*)d_ws;                               // 32*128 fp32 = 16 KB
  uint4* wfrag = (uint4*)((char*)d_ws + 32 * EMB * 4);       // 320 KB B-fragments

  hipLaunchKernelGGL(out_init_kernel, dim3(1), dim3(64), 0, stream, out, b_pred);
  hipLaunchKernelGGL(lin_kernel, dim3(32), dim3(EMB), 0, stream, emb_x, w_ti, b_ti, lin32);
  hipLaunchKernelGGL(wfrag_kernel, dim3(80), dim3(256), 0, stream, w_conv, wfrag);
  hipLaunchKernelGGL(i2gnn_mfma, dim3(4096), dim3(256), 0, stream,
                     x, edge_attr, tuplefeat, emb_x, emb_tf, emb_ea, lin32,
                     b_conv, w_pred, wfrag, out);
}